// Round 1
// baseline (996.998 us; speedup 1.0000x reference)
//
#include <hip/hip_runtime.h>

// MyVariableRNN: 5-layer GRU (H=16) over T=512, B=512, D=128, then FC to C=2.
// Key insight: output row b is exactly b_fc unless lengths[b]==T (final-state
// mask in the reference). Only ~2 rows qualify -> latency-bound sequential scan.

constexpr int kB = 512, kT = 512, kD = 128, kH = 16, kL = 5, kC = 2, kG = 48;
constexpr int kChunk = 128, kThreads = 256;

__device__ __forceinline__ float rl(float v, int lane) {
    return __int_as_float(__builtin_amdgcn_readlane(__float_as_int(v), lane));
}
__device__ __forceinline__ float bperm(float v, int addr_bytes) {
    return __int_as_float(__builtin_amdgcn_ds_bpermute(addr_bytes, __float_as_int(v)));
}

extern "C" __global__ void __launch_bounds__(kThreads, 1)
gru_all(const float* __restrict__ x, const int* __restrict__ len,
        const float* __restrict__ Wih0, const float* __restrict__ Wihr,
        const float* __restrict__ Whh, const float* __restrict__ bih,
        const float* __restrict__ bhh, const float* __restrict__ Wfc,
        const float* __restrict__ bfc, float* __restrict__ out)
{
    const int b = blockIdx.x;
    const int tid = threadIdx.x;

    if (len[b] != kT) {              // uniform per block: output is just b_fc
        if (tid < kC) out[b * kC + tid] = bfc[tid];
        return;
    }

    __shared__ float XG[kChunk][kG];  // input-projection buffer for one chunk (24 KB)
    __shared__ float Y[kT][kH];       // previous layer's full output sequence (32 KB)

    const int lane = tid & 63;
    const int gc = (lane < kG) ? lane : (kG - 1);   // clamp idle lanes 48-63
    const int aR = (lane & 15) * 4;           // bpermute addr: read r from lanes 0-15
    const int aZ = ((lane & 15) + 16) * 4;    // read z from lanes 16-31
    const int aN = ((lane & 15) + 32) * 4;    // read n from lanes 32-47

    float hcur = 0.0f;       // lane j<16 holds h[j]
    float wreg[kH];          // lane g holds W_hh[l][g][0..15]
    float bh = 0.0f;

    for (int l = 0; l < kL; ++l) {
        if (tid < 64) {
            const float* wrow = Whh + (size_t)(l * kG + gc) * kH;
            #pragma unroll
            for (int k = 0; k < kH; ++k) wreg[k] = wrow[k];
            bh = bhh[l * kG + gc];
            hcur = 0.0f;
        }
        for (int c0 = 0; c0 < kT; c0 += kChunk) {
            // ---- input projection for this chunk: all 256 threads ----
            if (l == 0) {
                for (int i = tid; i < kChunk * kG; i += kThreads) {
                    int tt = i / kG, g = i - tt * kG;
                    const float4* xr4 = (const float4*)(x + ((size_t)b * kT + (c0 + tt)) * kD);
                    const float4* wr4 = (const float4*)(Wih0 + (size_t)g * kD);
                    float4 a = {0.f, 0.f, 0.f, 0.f};
                    #pragma unroll 8
                    for (int k = 0; k < kD / 4; ++k) {
                        float4 xv = xr4[k], wv = wr4[k];
                        a.x = fmaf(xv.x, wv.x, a.x);
                        a.y = fmaf(xv.y, wv.y, a.y);
                        a.z = fmaf(xv.z, wv.z, a.z);
                        a.w = fmaf(xv.w, wv.w, a.w);
                    }
                    XG[tt][g] = bih[g] + ((a.x + a.y) + (a.z + a.w));
                }
            } else {
                const float* wih = Wihr + (size_t)(l - 1) * kG * kH;
                const float* bi  = bih + l * kG;
                for (int i = tid; i < kChunk * kG; i += kThreads) {
                    int tt = i / kG, g = i - tt * kG;
                    const float4* yv4 = (const float4*)(&Y[c0 + tt][0]);
                    const float4* wr4 = (const float4*)(wih + g * kH);
                    float acc = bi[g];
                    #pragma unroll
                    for (int k = 0; k < kH / 4; ++k) {
                        float4 yv = yv4[k], wv = wr4[k];
                        acc = fmaf(yv.x, wv.x, acc);
                        acc = fmaf(yv.y, wv.y, acc);
                        acc = fmaf(yv.z, wv.z, acc);
                        acc = fmaf(yv.w, wv.w, acc);
                    }
                    XG[tt][g] = acc;
                }
            }
            __syncthreads();
            // ---- sequential scan over the chunk: wave 0 only ----
            if (tid < 64) {
                float xg = XG[0][gc];
                for (int tt = 0; tt < kChunk; ++tt) {
                    float xg_n = (tt + 1 < kChunk) ? XG[tt + 1][gc] : 0.0f; // prefetch
                    // hidden matvec: hg[g] = b_hh[g] + sum_k Whh[g][k] * h[k]
                    float a0 = bh, a1 = 0.f, a2 = 0.f, a3 = 0.f;
                    #pragma unroll
                    for (int k = 0; k < 4; ++k) {
                        a0 = fmaf(rl(hcur, k),      wreg[k],      a0);
                        a1 = fmaf(rl(hcur, k + 4),  wreg[k + 4],  a1);
                        a2 = fmaf(rl(hcur, k + 8),  wreg[k + 8],  a2);
                        a3 = fmaf(rl(hcur, k + 12), wreg[k + 12], a3);
                    }
                    float hg = (a0 + a1) + (a2 + a3);
                    float s = xg + hg;
                    // sigmoid (meaningful in lanes 0-31)
                    float e   = __expf(-s);
                    float sig = __builtin_amdgcn_rcpf(1.0f + e);
                    float rb  = bperm(sig, aR);             // r[lane&15] everywhere
                    // n = tanh(xn + r*hn)  (meaningful in lanes 32-47)
                    float narg = fmaf(rb, hg, xg);
                    float e2 = __expf(2.0f * narg);
                    float n  = 1.0f - 2.0f * __builtin_amdgcn_rcpf(e2 + 1.0f);
                    float zb = bperm(sig, aZ);              // z[lane&15]
                    float nb = bperm(n,   aN);              // n[lane&15]
                    // h' = n + z*(h - n)   (meaningful in lanes 0-15)
                    hcur = fmaf(zb, hcur - nb, nb);
                    if (l < kL - 1 && lane < kH) Y[c0 + tt][lane] = hcur;
                    xg = xg_n;
                }
            }
            __syncthreads();
        }
    }
    // FC epilogue: out[b][c] = b_fc[c] + sum_j W_fc[c][j] * h[j]
    if (tid < kC) {
        float acc = bfc[tid];
        #pragma unroll
        for (int j = 0; j < kH; ++j)
            acc = fmaf(rl(hcur, j), Wfc[tid * kH + j], acc);
        out[b * kC + tid] = acc;
    }
}

extern "C" void kernel_launch(void* const* d_in, const int* in_sizes, int n_in,
                              void* d_out, int out_size, void* d_ws, size_t ws_size,
                              hipStream_t stream) {
    const float* x    = (const float*)d_in[0];
    const int*   len  = (const int*)d_in[1];
    const float* Wih0 = (const float*)d_in[2];
    const float* Wihr = (const float*)d_in[3];
    const float* Whh  = (const float*)d_in[4];
    const float* bih  = (const float*)d_in[5];
    const float* bhh  = (const float*)d_in[6];
    const float* Wfc  = (const float*)d_in[7];
    const float* bfc  = (const float*)d_in[8];
    float* outp = (float*)d_out;

    hipLaunchKernelGGL(gru_all, dim3(kB), dim3(kThreads), 0, stream,
                       x, len, Wih0, Wihr, Whh, bih, bhh, Wfc, bfc, outp);
}

// Round 2
// 474.435 us; speedup vs baseline: 2.1014x; 2.1014x over previous
//
#include <hip/hip_runtime.h>

// 5-layer GRU (H=16) over T=512; only rows with length==T matter (~2 of 512).
// Latency-bound -> (a) permlane swaps instead of ds_bpermute in the recurrence,
// (b) wavefront pipeline: wave l scans layer l, chunk c, in phase p=c+l+1;
// waves 5-7 produce layer-0 input projections (D=128) one chunk ahead.

constexpr int kB = 512, kT = 512, kD = 128, kH = 16, kL = 5, kC = 2, kG = 48;
constexpr int kChunk = 32, kNC = kT / kChunk, kThreads = 512, kPhases = kNC + kL;

typedef unsigned uint2v __attribute__((ext_vector_type(2)));

__device__ __forceinline__ float rl(float v, int lane) {
    return __int_as_float(__builtin_amdgcn_readlane(__float_as_int(v), lane));
}

#if __has_builtin(__builtin_amdgcn_permlane32_swap) && __has_builtin(__builtin_amdgcn_permlane16_swap)
// Direction-agnostic "value from lane^K partner": with identical inputs, the two
// swap outputs are {self-dup, partner-dup} in some order; pick the candidate
// whose BITS differ from self (bit-equal => both correct). No NaNs arise here.
__device__ __forceinline__ float sel_other(uint2v r, float self) {
    unsigned s = __float_as_uint(self);
    return __uint_as_float((r[0] == s) ? r[1] : r[0]);
}
__device__ __forceinline__ float xor32(float v) {
    uint2v r = __builtin_amdgcn_permlane32_swap(__float_as_uint(v), __float_as_uint(v), false, false);
    return sel_other(r, v);
}
__device__ __forceinline__ float xor16(float v) {
    uint2v r = __builtin_amdgcn_permlane16_swap(__float_as_uint(v), __float_as_uint(v), false, false);
    return sel_other(r, v);
}
#else
__device__ __forceinline__ float bperm_xor(float v, int xmask) {
    int lane = threadIdx.x & 63;
    return __int_as_float(__builtin_amdgcn_ds_bpermute((lane ^ xmask) * 4, __float_as_int(v)));
}
__device__ __forceinline__ float xor32(float v) { return bperm_xor(v, 32); }
__device__ __forceinline__ float xor16(float v) { return bperm_xor(v, 16); }
#endif

// One 32-step GRU scan over a chunk. Lane g<48 owns gate-row g (r:0-15, z:16-31,
// n:32-47); h lives in lanes 0-15. Matvec via readlane SGPR broadcasts.
template<bool WRITE_Y>
__device__ __forceinline__ float scan_chunk(float h, const float (*__restrict__ xgp)[kG],
                                            float (*__restrict__ yo)[kH],
                                            const float (&wreg)[kH], float bh,
                                            int lane, int g)
{
    float xg = xgp[0][g];
    #pragma unroll 4
    for (int tt = 0; tt < kChunk; ++tt) {
        float xg_n = (tt + 1 < kChunk) ? xgp[tt + 1][g] : 0.0f;  // prefetch
        // hg[g] = b_hh[g] + sum_k Whh[g][k] * h[k]
        float a0 = bh, a1 = 0.f, a2 = 0.f, a3 = 0.f;
        #pragma unroll
        for (int k = 0; k < 4; ++k) {
            a0 = fmaf(rl(h, k),      wreg[k],      a0);
            a1 = fmaf(rl(h, k + 4),  wreg[k + 4],  a1);
            a2 = fmaf(rl(h, k + 8),  wreg[k + 8],  a2);
            a3 = fmaf(rl(h, k + 12), wreg[k + 12], a3);
        }
        float hg = (a0 + a1) + (a2 + a3);
        float s = xg + hg;
        float e = __expf(-s);
        float sig = __builtin_amdgcn_rcpf(1.0f + e);       // r in 0-15, z in 16-31
        float rb = xor32(sig);                             // n-lanes get r[j]
        float narg = fmaf(rb, hg, xg);                     // n-lanes: xn + r*hn
        float e2 = __expf(2.0f * narg);
        float nv = 1.0f - 2.0f * __builtin_amdgcn_rcpf(e2 + 1.0f);  // tanh
        float nb = xor32(nv);                              // h-lanes get n[j]
        float zb = xor16(sig);                             // h-lanes get z[j]
        h = fmaf(zb, h - nb, nb);                          // h' = n + z*(h-n)
        if (WRITE_Y && lane < kH) yo[tt][lane] = h;
        xg = xg_n;
    }
    return h;
}

extern "C" __global__ void __launch_bounds__(kThreads, 1)
gru_pipe(const float* __restrict__ x, const int* __restrict__ len,
         const float* __restrict__ Wih0, const float* __restrict__ Wihr,
         const float* __restrict__ Whh, const float* __restrict__ bih,
         const float* __restrict__ bhh, const float* __restrict__ Wfc,
         const float* __restrict__ bfc, float* __restrict__ out)
{
    const int b = blockIdx.x;
    const int tid = threadIdx.x;

    if (len[b] != kT) {                 // uniform: output is just b_fc
        if (tid < kC) out[b * kC + tid] = bfc[tid];
        return;
    }

    __shared__ float XG0[2][kChunk][kG];        // layer-0 xg ring (12 KB)
    __shared__ float Yr[kL - 1][2][kChunk][kH]; // layer-output rings (16 KB)
    __shared__ float XB[kL - 1][kChunk][kG];    // per-wave xg buffers, layers 1-4 (24 KB)
    __shared__ float hfin[kH];

    const int wid = tid >> 6, lane = tid & 63;
    const int g = (lane < kG) ? lane : (kG - 1);

    float wreg[kH], wih[kH];
    float bh = 0.f, bi = 0.f, hcur = 0.f;

    if (wid < kL) {
        const float* wrow = Whh + (size_t)(wid * kG + g) * kH;
        #pragma unroll
        for (int k = 0; k < kH; ++k) wreg[k] = wrow[k];
        bh = bhh[wid * kG + g];
        if (wid > 0) {
            const float* wr2 = Wihr + (size_t)((wid - 1) * kG + g) * kH;
            #pragma unroll
            for (int k = 0; k < kH; ++k) wih[k] = wr2[k];
            bi = bih[wid * kG + g];
        }
        __builtin_amdgcn_s_setprio(1);   // favor scan waves over producers
    }

    for (int p = 0; p < kPhases; ++p) {
        if (wid >= kL) {
            // ---- producers: layer-0 input projection for chunk p ----
            if (p < kNC) {
                const int pid = tid - kL * 64;      // 0..191
                const int c0 = p * kChunk;
                float* dst = &XG0[p & 1][0][0];
                #pragma unroll
                for (int it = 0; it < 8; ++it) {
                    int item = pid + 192 * it;      // 0..1535
                    int tt = item / kG, gg = item - tt * kG;
                    const float4* xr = (const float4*)(x + ((size_t)b * kT + c0 + tt) * kD);
                    const float4* wr = (const float4*)(Wih0 + (size_t)gg * kD);
                    float ax = 0.f, ay = 0.f, az = 0.f, aw = 0.f;
                    #pragma unroll 8
                    for (int k = 0; k < kD / 4; ++k) {
                        float4 xv = xr[k], wv = wr[k];
                        ax = fmaf(xv.x, wv.x, ax);
                        ay = fmaf(xv.y, wv.y, ay);
                        az = fmaf(xv.z, wv.z, az);
                        aw = fmaf(xv.w, wv.w, aw);
                    }
                    dst[tt * kG + gg] = bih[gg] + ((ax + ay) + (az + aw));
                }
            }
        } else if (wid == 0) {
            int c = p - 1;
            if (0 <= c && c < kNC)
                hcur = scan_chunk<true>(hcur, XG0[c & 1], Yr[0][c & 1], wreg, bh, lane, g);
        } else {
            int c = p - 1 - wid;
            if (0 <= c && c < kNC) {
                // ---- project this chunk's xg from previous layer's output ----
                const float (*yp)[kH] = Yr[wid - 1][c & 1];
                float (*xb)[kG] = XB[wid - 1];
                if (lane < kG) {
                    for (int tt = 0; tt < kChunk; ++tt) {
                        const float4* y4 = (const float4*)&yp[tt][0];  // broadcast reads
                        float4 y0 = y4[0], y1 = y4[1], y2 = y4[2], y3 = y4[3];
                        float p0 = bi, p1 = 0.f, p2 = 0.f, p3 = 0.f;
                        p0 = fmaf(y0.x, wih[0],  p0); p0 = fmaf(y0.y, wih[1],  p0);
                        p0 = fmaf(y0.z, wih[2],  p0); p0 = fmaf(y0.w, wih[3],  p0);
                        p1 = fmaf(y1.x, wih[4],  p1); p1 = fmaf(y1.y, wih[5],  p1);
                        p1 = fmaf(y1.z, wih[6],  p1); p1 = fmaf(y1.w, wih[7],  p1);
                        p2 = fmaf(y2.x, wih[8],  p2); p2 = fmaf(y2.y, wih[9],  p2);
                        p2 = fmaf(y2.z, wih[10], p2); p2 = fmaf(y2.w, wih[11], p2);
                        p3 = fmaf(y3.x, wih[12], p3); p3 = fmaf(y3.y, wih[13], p3);
                        p3 = fmaf(y3.z, wih[14], p3); p3 = fmaf(y3.w, wih[15], p3);
                        xb[tt][g] = (p0 + p1) + (p2 + p3);
                    }
                }
                asm volatile("s_waitcnt lgkmcnt(0)" ::: "memory");
                if (wid < kL - 1)
                    hcur = scan_chunk<true>(hcur, xb, Yr[wid][c & 1], wreg, bh, lane, g);
                else
                    hcur = scan_chunk<false>(hcur, xb, nullptr, wreg, bh, lane, g);
            }
        }
        __syncthreads();
    }

    if (wid == kL - 1 && lane < kH) hfin[lane] = hcur;
    __syncthreads();

    if (tid < kC) {
        float acc = bfc[tid];
        #pragma unroll
        for (int j = 0; j < kH; ++j)
            acc = fmaf(hfin[j], Wfc[tid * kH + j], acc);
        out[b * kC + tid] = acc;
    }
}

extern "C" void kernel_launch(void* const* d_in, const int* in_sizes, int n_in,
                              void* d_out, int out_size, void* d_ws, size_t ws_size,
                              hipStream_t stream) {
    const float* x    = (const float*)d_in[0];
    const int*   len  = (const int*)d_in[1];
    const float* Wih0 = (const float*)d_in[2];
    const float* Wihr = (const float*)d_in[3];
    const float* Whh  = (const float*)d_in[4];
    const float* bih  = (const float*)d_in[5];
    const float* bhh  = (const float*)d_in[6];
    const float* Wfc  = (const float*)d_in[7];
    const float* bfc  = (const float*)d_in[8];
    float* outp = (float*)d_out;

    hipLaunchKernelGGL(gru_pipe, dim3(kB), dim3(kThreads), 0, stream,
                       x, len, Wih0, Wihr, Whh, bih, bhh, Wfc, bfc, outp);
}

// Round 3
// 226.847 us; speedup vs baseline: 4.3950x; 2.0914x over previous
//
#include <hip/hip_runtime.h>

// 5-layer GRU (H=16), T=512; only rows with length==T matter (~2 of 512,
// and they form a PREFIX since lengths are sorted descending).
// R3: layer-0 input projection moved to a parallel prologue kernel (proj0 ->
// d_ws); pipeline kernel is 5 scan waves only (no producer interference).

constexpr int kB = 512, kT = 512, kD = 128, kH = 16, kL = 5, kC = 2, kG = 48;
constexpr int kChunk = 32, kNC = kT / kChunk, kThreads = 320, kPhases = kNC + kL - 1;

typedef unsigned uint2v __attribute__((ext_vector_type(2)));

__device__ __forceinline__ float rl(float v, int lane) {
    return __int_as_float(__builtin_amdgcn_readlane(__float_as_int(v), lane));
}

#if __has_builtin(__builtin_amdgcn_permlane32_swap) && __has_builtin(__builtin_amdgcn_permlane16_swap)
// Direction-agnostic partner select (validated: absmax 0 in R2).
__device__ __forceinline__ float sel_other(uint2v r, float self) {
    unsigned s = __float_as_uint(self);
    return __uint_as_float((r[0] == s) ? r[1] : r[0]);
}
__device__ __forceinline__ float xor32(float v) {
    uint2v r = __builtin_amdgcn_permlane32_swap(__float_as_uint(v), __float_as_uint(v), false, false);
    return sel_other(r, v);
}
__device__ __forceinline__ float xor16(float v) {
    uint2v r = __builtin_amdgcn_permlane16_swap(__float_as_uint(v), __float_as_uint(v), false, false);
    return sel_other(r, v);
}
#else
__device__ __forceinline__ float bperm_xor(float v, int xmask) {
    int lane = threadIdx.x & 63;
    return __int_as_float(__builtin_amdgcn_ds_bpermute((lane ^ xmask) * 4, __float_as_int(v)));
}
__device__ __forceinline__ float xor32(float v) { return bperm_xor(v, 32); }
__device__ __forceinline__ float xor16(float v) { return bperm_xor(v, 16); }
#endif

// 32-step GRU scan. Lane g<48 owns gate-row g (r:0-15, z:16-31, n:32-47);
// h lives in lanes 0-15. Matvec via readlane broadcasts.
template<bool WRITE_Y>
__device__ __forceinline__ float scan_chunk(float h, const float (*__restrict__ xgp)[kG],
                                            float (*__restrict__ yo)[kH],
                                            const float (&wreg)[kH], float bh,
                                            int lane, int g)
{
    float xg = xgp[0][g];
    #pragma unroll 4
    for (int tt = 0; tt < kChunk; ++tt) {
        float xg_n = (tt + 1 < kChunk) ? xgp[tt + 1][g] : 0.0f;  // prefetch
        float a0 = bh, a1 = 0.f, a2 = 0.f, a3 = 0.f;
        #pragma unroll
        for (int k = 0; k < 4; ++k) {
            a0 = fmaf(rl(h, k),      wreg[k],      a0);
            a1 = fmaf(rl(h, k + 4),  wreg[k + 4],  a1);
            a2 = fmaf(rl(h, k + 8),  wreg[k + 8],  a2);
            a3 = fmaf(rl(h, k + 12), wreg[k + 12], a3);
        }
        float hg = (a0 + a1) + (a2 + a3);
        float s = xg + hg;
        float e = __expf(-s);
        float sig = __builtin_amdgcn_rcpf(1.0f + e);       // r:0-15, z:16-31
        float rb = xor32(sig);                             // n-lanes get r
        float narg = fmaf(rb, hg, xg);
        float e2 = __expf(2.0f * narg);
        float nv = 1.0f - 2.0f * __builtin_amdgcn_rcpf(e2 + 1.0f);  // tanh
        float nb = xor32(nv);                              // h-lanes get n
        float zb = xor16(sig);                             // h-lanes get z
        h = fmaf(zb, h - nb, nb);                          // h' = n + z*(h-n)
        if (WRITE_Y && lane < kH) yo[tt][lane] = h;
        xg = xg_n;
    }
    return h;
}

// -------- prologue: xg0[b][t][g] = b_ih[g] + W_ih0[g,:].x[b,t,:] --------
extern "C" __global__ void __launch_bounds__(256, 1)
proj0(const float* __restrict__ x, const int* __restrict__ len,
      const float* __restrict__ Wih0, const float* __restrict__ bih,
      float* __restrict__ xg0, int qmax)
{
    const int blk = blockIdx.x;
    const int b = blk >> 3, s = blk & 7;        // 8 tiles of 64 t per row
    if (b >= qmax || len[b] != kT) return;
    const int tid = threadIdx.x;
    #pragma unroll 2
    for (int i = 0; i < 12; ++i) {
        int item = tid + 256 * i;               // item = t*48+g: lanes share t
        int t = item / kG, g = item - t * kG;   // -> x reads broadcast, W in L1
        const float4* xr = (const float4*)(x + ((size_t)b * kT + s * 64 + t) * kD);
        const float4* wr = (const float4*)(Wih0 + (size_t)g * kD);
        float a0 = 0.f, a1 = 0.f, a2 = 0.f, a3 = 0.f;
        #pragma unroll 8
        for (int k = 0; k < kD / 4; ++k) {
            float4 xv = xr[k], wv = wr[k];
            a0 = fmaf(xv.x, wv.x, a0);
            a1 = fmaf(xv.y, wv.y, a1);
            a2 = fmaf(xv.z, wv.z, a2);
            a3 = fmaf(xv.w, wv.w, a3);
        }
        xg0[((size_t)b * kT + s * 64 + t) * kG + g] = bih[g] + ((a0 + a1) + (a2 + a3));
    }
}

// Fallback (row qualifies but ws too small): wave 0 computes one chunk itself.
__device__ void proj_chunk_wave0(const float* __restrict__ x,
                                 const float* __restrict__ Wih0,
                                 const float* __restrict__ bih,
                                 int b, int c, int lane, float (*__restrict__ XW0)[kG])
{
    for (int i = 0; i < 24; ++i) {
        int item = lane + 64 * i;
        int t = item / kG, g = item - t * kG;
        const float4* xr = (const float4*)(x + ((size_t)b * kT + c * kChunk + t) * kD);
        const float4* wr = (const float4*)(Wih0 + (size_t)g * kD);
        float a0 = 0.f, a1 = 0.f, a2 = 0.f, a3 = 0.f;
        #pragma unroll 8
        for (int k = 0; k < kD / 4; ++k) {
            float4 xv = xr[k], wv = wr[k];
            a0 = fmaf(xv.x, wv.x, a0);
            a1 = fmaf(xv.y, wv.y, a1);
            a2 = fmaf(xv.z, wv.z, a2);
            a3 = fmaf(xv.w, wv.w, a3);
        }
        XW0[t][g] = bih[g] + ((a0 + a1) + (a2 + a3));
    }
}

extern "C" __global__ void __launch_bounds__(kThreads, 1)
gru_pipe2(const float* __restrict__ x, const int* __restrict__ len,
          const float* __restrict__ Wih0, const float* __restrict__ Wihr,
          const float* __restrict__ Whh, const float* __restrict__ bih,
          const float* __restrict__ bhh, const float* __restrict__ Wfc,
          const float* __restrict__ bfc, const float* __restrict__ xg0,
          float* __restrict__ out, int qmax)
{
    const int b = blockIdx.x;
    const int tid = threadIdx.x;

    if (len[b] != kT) {                 // uniform: output is just b_fc
        if (tid < kC) out[b * kC + tid] = bfc[tid];
        return;
    }

    __shared__ float XW0[kChunk][kG];           // wave-0 private xg buffer (6 KB)
    __shared__ float XB[kL - 1][kChunk][kG];    // per-wave xg buffers, layers 1-4 (24 KB)
    __shared__ float Yr[kL - 1][2][kChunk][kH]; // layer-output rings (16 KB)
    __shared__ float hfin[kH];

    const int wid = tid >> 6, lane = tid & 63;
    const int g = (lane < kG) ? lane : (kG - 1);
    const bool fast = (b < qmax);
    const float* xgb = xg0 + (size_t)b * kT * kG;

    float wreg[kH], wih[kH];
    float bh = 0.f, bi = 0.f, hcur = 0.f;

    {
        const float* wrow = Whh + (size_t)(wid * kG + g) * kH;
        #pragma unroll
        for (int k = 0; k < kH; ++k) wreg[k] = wrow[k];
        bh = bhh[wid * kG + g];
        if (wid > 0) {
            const float* wr2 = Wihr + (size_t)((wid - 1) * kG + g) * kH;
            #pragma unroll
            for (int k = 0; k < kH; ++k) wih[k] = wr2[k];
            bi = bih[wid * kG + g];
        }
    }

    // ---- prologue: chunk 0 into XW0 ----
    if (wid == 0) {
        if (fast) {
            #pragma unroll
            for (int i = 0; i < 6; ++i)
                ((float4*)XW0)[lane + 64 * i] = ((const float4*)xgb)[lane + 64 * i];
        } else {
            proj_chunk_wave0(x, Wih0, bih, b, 0, lane, XW0);
        }
    }
    __syncthreads();

    // ---- wavefront pipeline: wave l scans layer l, chunk c = p - l ----
    for (int p = 0; p < kPhases; ++p) {
        if (wid == 0) {
            int c = p;
            if (c < kNC) {
                float4 pf[6];
                const bool pre = fast && (c + 1 < kNC);
                if (pre) {     // T14: issue next chunk's loads before the scan
                    const float4* src = (const float4*)(xgb + (size_t)(c + 1) * kChunk * kG);
                    #pragma unroll
                    for (int i = 0; i < 6; ++i) pf[i] = src[lane + 64 * i];
                }
                hcur = scan_chunk<true>(hcur, XW0, Yr[0][c & 1], wreg, bh, lane, g);
                if (pre) {     // write-late: lands before next phase's reads
                    #pragma unroll
                    for (int i = 0; i < 6; ++i) ((float4*)XW0)[lane + 64 * i] = pf[i];
                } else if (!fast && c + 1 < kNC) {
                    proj_chunk_wave0(x, Wih0, bih, b, c + 1, lane, XW0);
                }
            }
        } else {
            int c = p - wid;
            if (0 <= c && c < kNC) {
                // project this chunk's xg from previous layer's output
                const float (*yp)[kH] = Yr[wid - 1][c & 1];
                float (*xb)[kG] = XB[wid - 1];
                if (lane < kG) {
                    for (int tt = 0; tt < kChunk; ++tt) {
                        const float4* y4 = (const float4*)&yp[tt][0];  // broadcast reads
                        float4 y0 = y4[0], y1 = y4[1], y2 = y4[2], y3 = y4[3];
                        float p0 = bi, p1 = 0.f, p2 = 0.f, p3 = 0.f;
                        p0 = fmaf(y0.x, wih[0],  p0); p0 = fmaf(y0.y, wih[1],  p0);
                        p0 = fmaf(y0.z, wih[2],  p0); p0 = fmaf(y0.w, wih[3],  p0);
                        p1 = fmaf(y1.x, wih[4],  p1); p1 = fmaf(y1.y, wih[5],  p1);
                        p1 = fmaf(y1.z, wih[6],  p1); p1 = fmaf(y1.w, wih[7],  p1);
                        p2 = fmaf(y2.x, wih[8],  p2); p2 = fmaf(y2.y, wih[9],  p2);
                        p2 = fmaf(y2.z, wih[10], p2); p2 = fmaf(y2.w, wih[11], p2);
                        p3 = fmaf(y3.x, wih[12], p3); p3 = fmaf(y3.y, wih[13], p3);
                        p3 = fmaf(y3.z, wih[14], p3); p3 = fmaf(y3.w, wih[15], p3);
                        xb[tt][g] = (p0 + p1) + (p2 + p3);
                    }
                }
                asm volatile("s_waitcnt lgkmcnt(0)" ::: "memory");
                if (wid < kL - 1)
                    hcur = scan_chunk<true>(hcur, xb, Yr[wid][c & 1], wreg, bh, lane, g);
                else
                    hcur = scan_chunk<false>(hcur, xb, nullptr, wreg, bh, lane, g);
            }
        }
        __syncthreads();
    }

    if (wid == kL - 1 && lane < kH) hfin[lane] = hcur;
    __syncthreads();

    if (tid < kC) {
        float acc = bfc[tid];
        #pragma unroll
        for (int j = 0; j < kH; ++j)
            acc = fmaf(hfin[j], Wfc[tid * kH + j], acc);
        out[b * kC + tid] = acc;
    }
}

extern "C" void kernel_launch(void* const* d_in, const int* in_sizes, int n_in,
                              void* d_out, int out_size, void* d_ws, size_t ws_size,
                              hipStream_t stream) {
    const float* x    = (const float*)d_in[0];
    const int*   len  = (const int*)d_in[1];
    const float* Wih0 = (const float*)d_in[2];
    const float* Wihr = (const float*)d_in[3];
    const float* Whh  = (const float*)d_in[4];
    const float* bih  = (const float*)d_in[5];
    const float* bhh  = (const float*)d_in[6];
    const float* Wfc  = (const float*)d_in[7];
    const float* bfc  = (const float*)d_in[8];
    float* outp = (float*)d_out;
    float* xg0  = (float*)d_ws;

    size_t per_row = (size_t)kT * kG * sizeof(float);
    int qmax = (int)((ws_size / per_row) < (size_t)kB ? (ws_size / per_row) : (size_t)kB);

    hipLaunchKernelGGL(proj0, dim3(kB * 8), dim3(256), 0, stream,
                       x, len, Wih0, bih, xg0, qmax);
    hipLaunchKernelGGL(gru_pipe2, dim3(kB), dim3(kThreads), 0, stream,
                       x, len, Wih0, Wihr, Whh, bih, bhh, Wfc, bfc, xg0, outp, qmax);
}

// Round 4
// 209.542 us; speedup vs baseline: 4.7580x; 1.0826x over previous
//
#include <hip/hip_runtime.h>

// 5-layer GRU (H=16), T=512; only rows with length==T matter (~2 of 512, a
// PREFIX since lengths sorted descending). proj0 precomputes layer-0 xg.
// gru_pipe3: lag-2 wavefront (wave l scans chunk c=p-2l); the projection of
// chunk c+1 (from prev layer's Y, or global xg0 for wave 0) is interleaved
// 1:1 into the scan steps -> hidden under the recurrence dependency chain.
// xg lives in 32 registers per wave (fully unrolled, static indexing).

constexpr int kB = 512, kT = 512, kD = 128, kH = 16, kL = 5, kC = 2, kG = 48;
constexpr int kChunk = 32, kNC = kT / kChunk, kThreads = 320;
constexpr int kPhases = kNC + 2 * (kL - 1);
constexpr int kYW = 64;   // padded Y row: all 64 lanes write, [16..63] is pad

typedef unsigned uint2v __attribute__((ext_vector_type(2)));

__device__ __forceinline__ float rl(float v, int lane) {
    return __int_as_float(__builtin_amdgcn_readlane(__float_as_int(v), lane));
}

#if __has_builtin(__builtin_amdgcn_permlane32_swap) && __has_builtin(__builtin_amdgcn_permlane16_swap)
// Direction-agnostic partner select (absmax 0 in R2/R3 -> keep proven form).
__device__ __forceinline__ float sel_other(uint2v r, float self) {
    unsigned s = __float_as_uint(self);
    return __uint_as_float((r[0] == s) ? r[1] : r[0]);
}
__device__ __forceinline__ float xor32(float v) {
    uint2v r = __builtin_amdgcn_permlane32_swap(__float_as_uint(v), __float_as_uint(v), false, false);
    return sel_other(r, v);
}
__device__ __forceinline__ float xor16(float v) {
    uint2v r = __builtin_amdgcn_permlane16_swap(__float_as_uint(v), __float_as_uint(v), false, false);
    return sel_other(r, v);
}
#else
__device__ __forceinline__ float bperm_xor(float v, int xmask) {
    int lane = threadIdx.x & 63;
    return __int_as_float(__builtin_amdgcn_ds_bpermute((lane ^ xmask) * 4, __float_as_int(v)));
}
__device__ __forceinline__ float xor32(float v) { return bperm_xor(v, 32); }
__device__ __forceinline__ float xor16(float v) { return bperm_xor(v, 16); }
#endif

// One GRU cell step. Lane g<48 owns gate-row g (r:0-15, z:16-31, n:32-47);
// h lives in lanes 0-15. Matvec via readlane SGPR broadcasts.
__device__ __forceinline__ float gru_step(float h, float xg,
                                          const float (&wreg)[kH], float bh) {
    float a0 = bh, a1 = 0.f, a2 = 0.f, a3 = 0.f;
    #pragma unroll
    for (int k = 0; k < 4; ++k) {
        a0 = fmaf(rl(h, k),      wreg[k],      a0);
        a1 = fmaf(rl(h, k + 4),  wreg[k + 4],  a1);
        a2 = fmaf(rl(h, k + 8),  wreg[k + 8],  a2);
        a3 = fmaf(rl(h, k + 12), wreg[k + 12], a3);
    }
    float hg = (a0 + a1) + (a2 + a3);
    float s = xg + hg;
    float e = __expf(-s);
    float sig = __builtin_amdgcn_rcpf(1.0f + e);       // r:0-15, z:16-31
    float rb = xor32(sig);                             // n-lanes get r
    float narg = fmaf(rb, hg, xg);
    float e2 = __expf(2.0f * narg);
    float nv = 1.0f - 2.0f * __builtin_amdgcn_rcpf(e2 + 1.0f);  // tanh
    float nb = xor32(nv);                              // h-lanes get n
    float zb = xor16(sig);                             // h-lanes get z
    return fmaf(zb, h - nb, nb);                       // h' = n + z*(h-n)
}

// Fused phase: scan chunk c from xgr registers while preparing chunk c+1's xg
// into the same registers (in-place: read xgr[tt] for scan, overwrite after).
// PREP: 0 none, 1 global load (wave 0), 2 project from prev layer's Y.
template<bool SCAN, int PREP, bool WY>
__device__ __forceinline__ float phase_body(
    float h, float (&xgr)[kChunk], const float* __restrict__ gsrc,
    const float (*__restrict__ yprev)[kYW], float (*__restrict__ yout)[kYW],
    const float (&wreg)[kH], float bh, const float (&wih)[kH], float bi,
    int lane)
{
    #pragma unroll
    for (int tt = 0; tt < kChunk; ++tt) {
        if (SCAN) {
            h = gru_step(h, xgr[tt], wreg, bh);
            if (WY) yout[tt][lane] = h;          // unconditional; pad absorbs 16-63
        }
        if (PREP == 1) {
            xgr[tt] = gsrc[(size_t)tt * kG];
        } else if (PREP == 2) {
            const float4* y4 = (const float4*)&yprev[tt][0];   // broadcast reads
            float4 y0 = y4[0], y1 = y4[1], y2 = y4[2], y3 = y4[3];
            float p0 = bi, p1 = 0.f, p2 = 0.f, p3 = 0.f;
            p0 = fmaf(y0.x, wih[0],  p0); p0 = fmaf(y0.y, wih[1],  p0);
            p0 = fmaf(y0.z, wih[2],  p0); p0 = fmaf(y0.w, wih[3],  p0);
            p1 = fmaf(y1.x, wih[4],  p1); p1 = fmaf(y1.y, wih[5],  p1);
            p1 = fmaf(y1.z, wih[6],  p1); p1 = fmaf(y1.w, wih[7],  p1);
            p2 = fmaf(y2.x, wih[8],  p2); p2 = fmaf(y2.y, wih[9],  p2);
            p2 = fmaf(y2.z, wih[10], p2); p2 = fmaf(y2.w, wih[11], p2);
            p3 = fmaf(y3.x, wih[12], p3); p3 = fmaf(y3.y, wih[13], p3);
            p3 = fmaf(y3.z, wih[14], p3); p3 = fmaf(y3.w, wih[15], p3);
            xgr[tt] = (p0 + p1) + (p2 + p3);
        }
    }
    return h;
}

// -------- prologue kernel: xg0[b][t][g] = b_ih[g] + W_ih0[g,:].x[b,t,:] -----
extern "C" __global__ void __launch_bounds__(256, 1)
proj0(const float* __restrict__ x, const int* __restrict__ len,
      const float* __restrict__ Wih0, const float* __restrict__ bih,
      float* __restrict__ xg0, int qmax)
{
    const int blk = blockIdx.x;
    const int b = blk >> 4, s = blk & 15;       // 16 tiles of 32 t per row
    if (b >= qmax || len[b] != kT) return;
    const int tid = threadIdx.x;
    #pragma unroll
    for (int i = 0; i < 6; ++i) {
        int item = tid + 256 * i;               // item = t*48+g
        int t = item / kG, g = item - t * kG;
        const float4* xr = (const float4*)(x + ((size_t)b * kT + s * 32 + t) * kD);
        const float4* wr = (const float4*)(Wih0 + (size_t)g * kD);
        float a0 = 0.f, a1 = 0.f, a2 = 0.f, a3 = 0.f;
        #pragma unroll 8
        for (int k = 0; k < kD / 4; ++k) {
            float4 xv = xr[k], wv = wr[k];
            a0 = fmaf(xv.x, wv.x, a0);
            a1 = fmaf(xv.y, wv.y, a1);
            a2 = fmaf(xv.z, wv.z, a2);
            a3 = fmaf(xv.w, wv.w, a3);
        }
        xg0[((size_t)b * kT + s * 32 + t) * kG + g] = bih[g] + ((a0 + a1) + (a2 + a3));
    }
}

// Fallback (ws too small for this row): wave 0 computes one chunk from x.
__device__ void proj_chunk_wave0(const float* __restrict__ x,
                                 const float* __restrict__ Wih0,
                                 const float* __restrict__ bih,
                                 int b, int c, int lane, float (*__restrict__ XW0)[kG])
{
    for (int i = 0; i < 24; ++i) {
        int item = lane + 64 * i;
        int t = item / kG, g = item - t * kG;
        const float4* xr = (const float4*)(x + ((size_t)b * kT + c * kChunk + t) * kD);
        const float4* wr = (const float4*)(Wih0 + (size_t)g * kD);
        float a0 = 0.f, a1 = 0.f, a2 = 0.f, a3 = 0.f;
        #pragma unroll 8
        for (int k = 0; k < kD / 4; ++k) {
            float4 xv = xr[k], wv = wr[k];
            a0 = fmaf(xv.x, wv.x, a0);
            a1 = fmaf(xv.y, wv.y, a1);
            a2 = fmaf(xv.z, wv.z, a2);
            a3 = fmaf(xv.w, wv.w, a3);
        }
        XW0[t][g] = bih[g] + ((a0 + a1) + (a2 + a3));
    }
}

__device__ __forceinline__ void barrier_lgkm() {
    asm volatile("s_waitcnt lgkmcnt(0)" ::: "memory");
    __builtin_amdgcn_s_barrier();
}

extern "C" __global__ void __launch_bounds__(kThreads, 1)
gru_pipe3(const float* __restrict__ x, const int* __restrict__ len,
          const float* __restrict__ Wih0, const float* __restrict__ Wihr,
          const float* __restrict__ Whh, const float* __restrict__ bih,
          const float* __restrict__ bhh, const float* __restrict__ Wfc,
          const float* __restrict__ bfc, const float* __restrict__ xg0,
          float* __restrict__ out, int qmax)
{
    const int b = blockIdx.x;
    const int tid = threadIdx.x;

    if (len[b] != kT) {                 // uniform: output is just b_fc
        if (tid < kC) out[b * kC + tid] = bfc[tid];
        return;
    }

    __shared__ float Yr[kL - 1][2][kChunk][kYW];  // 64 KB, padded rows
    __shared__ float XW0[kChunk][kG];             // 6 KB, fallback only
    __shared__ float hfin[kH];

    const int wid = tid >> 6, lane = tid & 63;
    const int g = (lane < kG) ? lane : (kG - 1);
    const bool fast = (b < qmax);
    const float* xgb = xg0 + (size_t)b * kT * kG + g;

    float wreg[kH], wih[kH];
    float bh, bi = 0.f, h = 0.f;
    {
        const float* wrow = Whh + (size_t)(wid * kG + g) * kH;
        #pragma unroll
        for (int k = 0; k < kH; ++k) wreg[k] = wrow[k];
        bh = bhh[wid * kG + g];
        if (wid > 0) {
            const float* wr2 = Wihr + (size_t)((wid - 1) * kG + g) * kH;
            #pragma unroll
            for (int k = 0; k < kH; ++k) wih[k] = wr2[k];
            bi = bih[wid * kG + g];
        } else {
            #pragma unroll
            for (int k = 0; k < kH; ++k) wih[k] = 0.f;
        }
    }

    float xgr[kChunk];
    // ---- preload chunk 0 into wave-0 registers ----
    if (wid == 0) {
        if (fast) {
            #pragma unroll
            for (int tt = 0; tt < kChunk; ++tt) xgr[tt] = xgb[(size_t)tt * kG];
        } else {
            proj_chunk_wave0(x, Wih0, bih, b, 0, lane, XW0);
            asm volatile("s_waitcnt lgkmcnt(0)" ::: "memory");
            #pragma unroll
            for (int tt = 0; tt < kChunk; ++tt) xgr[tt] = XW0[tt][g];
        }
    }

    // ---- lag-2 wavefront: wave l scans chunk c = p - 2l ----
    for (int p = 0; p < kPhases; ++p) {
        const int c = (wid == 0) ? p : p - 2 * wid;
        const bool sc = (c >= 0 && c < kNC);
        const bool pr = (c + 1 >= 0 && c + 1 < kNC);
        if (wid == 0) {
            float (*yo)[kYW] = Yr[0][c & 1];
            if (fast) {
                const float* gsrc = xgb + (size_t)(c + 1) * kChunk * kG;
                if (sc && pr)
                    h = phase_body<true, 1, true>(h, xgr, gsrc, nullptr, yo, wreg, bh, wih, bi, lane);
                else if (sc)
                    h = phase_body<true, 0, true>(h, xgr, nullptr, nullptr, yo, wreg, bh, wih, bi, lane);
            } else {
                if (sc)
                    h = phase_body<true, 0, true>(h, xgr, nullptr, nullptr, yo, wreg, bh, wih, bi, lane);
                if (pr) {
                    proj_chunk_wave0(x, Wih0, bih, b, c + 1, lane, XW0);
                    asm volatile("s_waitcnt lgkmcnt(0)" ::: "memory");
                    #pragma unroll
                    for (int tt = 0; tt < kChunk; ++tt) xgr[tt] = XW0[tt][g];
                }
            }
        } else {
            const float (*yp)[kYW] = Yr[wid - 1][(c + 1) & 1];
            float (*yo)[kYW] = Yr[(wid < kL - 1) ? wid : 0][c & 1];  // dummy if WY=false
            if (wid < kL - 1) {
                if (sc && pr)
                    h = phase_body<true, 2, true>(h, xgr, nullptr, yp, yo, wreg, bh, wih, bi, lane);
                else if (sc)
                    h = phase_body<true, 0, true>(h, xgr, nullptr, yp, yo, wreg, bh, wih, bi, lane);
                else if (pr)
                    h = phase_body<false, 2, false>(h, xgr, nullptr, yp, yo, wreg, bh, wih, bi, lane);
            } else {
                if (sc && pr)
                    h = phase_body<true, 2, false>(h, xgr, nullptr, yp, yo, wreg, bh, wih, bi, lane);
                else if (sc)
                    h = phase_body<true, 0, false>(h, xgr, nullptr, yp, yo, wreg, bh, wih, bi, lane);
                else if (pr)
                    h = phase_body<false, 2, false>(h, xgr, nullptr, yp, yo, wreg, bh, wih, bi, lane);
            }
        }
        barrier_lgkm();   // lgkm-only: wave-0 global prefetch stays in flight
    }

    if (wid == kL - 1 && lane < kH) hfin[lane] = h;
    __syncthreads();

    if (tid < kC) {
        float acc = bfc[tid];
        #pragma unroll
        for (int j = 0; j < kH; ++j)
            acc = fmaf(hfin[j], Wfc[tid * kH + j], acc);
        out[b * kC + tid] = acc;
    }
}

extern "C" void kernel_launch(void* const* d_in, const int* in_sizes, int n_in,
                              void* d_out, int out_size, void* d_ws, size_t ws_size,
                              hipStream_t stream) {
    const float* x    = (const float*)d_in[0];
    const int*   len  = (const int*)d_in[1];
    const float* Wih0 = (const float*)d_in[2];
    const float* Wihr = (const float*)d_in[3];
    const float* Whh  = (const float*)d_in[4];
    const float* bih  = (const float*)d_in[5];
    const float* bhh  = (const float*)d_in[6];
    const float* Wfc  = (const float*)d_in[7];
    const float* bfc  = (const float*)d_in[8];
    float* outp = (float*)d_out;
    float* xg0  = (float*)d_ws;

    size_t per_row = (size_t)kT * kG * sizeof(float);
    int qmax = (int)((ws_size / per_row) < (size_t)kB ? (ws_size / per_row) : (size_t)kB);

    hipLaunchKernelGGL(proj0, dim3(kB * 16), dim3(256), 0, stream,
                       x, len, Wih0, bih, xg0, qmax);
    hipLaunchKernelGGL(gru_pipe3, dim3(kB), dim3(kThreads), 0, stream,
                       x, len, Wih0, Wihr, Whh, bih, bhh, Wfc, bfc, xg0, outp, qmax);
}